// Round 9
// baseline (287.566 us; speedup 1.0000x reference)
//
#include <hip/hip_runtime.h>

#define N_NODES 100000
#define N_EDGES 1600000
#define F 128
#define M_PAD 100032       // N_NODES rounded up to 64
#define NCB 782            // buckets = ceil(N_NODES/128)
#define CAP 2432           // padded bucket capacity (mean 2048, sigma 45, +8.5 sigma)
#define EPB 2048           // edges per multisplit block (halved: occupancy 3->6 blocks/CU)
#define MS_BLOCKS 782      // ceil(N_EDGES/EPB)
#define FB_BLOCKS 6250     // feats conv: 1.6M uint4 / 256
#define W_BLOCKS 64        // W conv: 16384 / 256
#define CC_BLOCKS 4        // ccur init: ceil(NCB/256)

typedef __attribute__((ext_vector_type(8))) short short8;
typedef __attribute__((ext_vector_type(4))) float float4v;

__device__ __forceinline__ unsigned pack_bf16(float x, float y) {
    unsigned ux = __float_as_uint(x), uy = __float_as_uint(y);
    ux = (ux + 0x7fffu + ((ux >> 16) & 1u)) >> 16;       // RNE
    uy = (uy + 0x7fffu + ((uy >> 16) & 1u)) >> 16;
    return ux | (uy << 16);
}

// ---- prep: feats->bf16 (4 pairs/thread), W->Wb bf16, ccur init to bucket bases ----
__global__ __launch_bounds__(256) void prep_kernel(
    const float4* __restrict__ feats4, uint4* __restrict__ featsb4,
    const float* __restrict__ W1, const float* __restrict__ W2,
    unsigned* __restrict__ Wbu, int* __restrict__ ccur)
{
    int b = blockIdx.x, t = threadIdx.x;
    if (b < FB_BLOCKS) {
        int i = b * 256 + t;                       // < 1,600,000 exactly
        float4 v0 = feats4[2 * i], v1 = feats4[2 * i + 1];
        featsb4[i] = make_uint4(pack_bf16(v0.x, v0.y), pack_bf16(v0.z, v0.w),
                                pack_bf16(v1.x, v1.y), pack_bf16(v1.z, v1.w));
    } else if (b < FB_BLOCKS + W_BLOCKS) {
        int i = (b - FB_BLOCKS) * 256 + t;         // < 16384 exactly
        int j = i >> 7, c = i & 127;
        const float* s = (c < 64) ? &W1[j * 128 + 2 * c] : &W2[j * 128 + 2 * (c - 64)];
        Wbu[i] = pack_bf16(s[0], s[1]);
    } else {
        int i = (b - FB_BLOCKS - W_BLOCKS) * 256 + t;
        if (i < NCB) ccur[i] = i * CAP;
    }
}

// ---- Pass A: multisplit into 128-node buckets; dst-low(7b) in bits 24..31.
//      ccur holds absolute positions (init b*CAP).
//      LDS 26.7 KB -> 6 blocks/CU (24 waves/CU, was 12) ----
__global__ __launch_bounds__(256) void passA_kernel(
    const int* __restrict__ esrc, const int* __restrict__ edst,
    const float* __restrict__ evals, int* __restrict__ ccur,
    int2* __restrict__ srtA)
{
    __shared__ int2 sv[EPB];              // 16 KB
    __shared__ unsigned short bkt[EPB];   //  4 KB
    __shared__ int h[NCB], lo[NCB];       //  6.3 KB  (total 26.7 KB)

    const int t = threadIdx.x;
    const int base = blockIdx.x * EPB;
    const int cnt = min(EPB, N_EDGES - base);

    for (int i = t; i < NCB; i += 256) h[i] = 0;
    __syncthreads();

    int rsrc[8], rdst[8], rrank[8];
    float rval[8];
#pragma unroll
    for (int i = 0; i < 8; i++) {
        int e = base + i * 256 + t;
        if (e < N_EDGES) {
            rsrc[i] = esrc[e];
            rdst[i] = edst[e];
            rval[i] = evals[e];
            rrank[i] = atomicAdd(&h[rdst[i] >> 7], 1);
        } else rdst[i] = -1;
    }
    __syncthreads();

    if (t < 64) {   // exclusive scan of h by wave 0
        int carry = 0;
        for (int b0 = 0; b0 < NCB; b0 += 64) {
            int i = b0 + t;
            int x = (i < NCB) ? h[i] : 0;
            int v = x;
#pragma unroll
            for (int d = 1; d < 64; d <<= 1) {
                int y = __shfl_up(v, d);
                if (t >= d) v += y;
            }
            if (i < NCB) lo[i] = v - x + carry;
            carry += __shfl(v, 63);
        }
    }
    __syncthreads();

#pragma unroll
    for (int i = 0; i < 8; i++) {
        if (rdst[i] >= 0) {
            int b = rdst[i] >> 7;
            int s = lo[b] + rrank[i];
            sv[s]  = make_int2(rsrc[i] | ((rdst[i] & 127) << 24),
                               __float_as_int(rval[i]));
            bkt[s] = (unsigned short)b;
        }
    }
    __syncthreads();     // protect lo[] reads above before overwriting below

    // reserve global space; fold dest-base into lo: lo[b] := gdest - local_lo
    for (int b = t; b < NCB; b += 256) {
        int c = h[b];
        if (c) {
            int g = atomicAdd(&ccur[b], c);   // absolute position
            lo[b] = g - lo[b];
        }
    }
    __syncthreads();

    for (int s = t; s < cnt; s += 256)
        srtA[lo[bkt[s]] + s] = sv[s];
}

// ---- fused sort+gather per 128-node bucket:
//      LDS fine sort (int atomics only) -> register-accum gather -> bf16 Abig.
//      LDS 20.5 KB -> 8 blocks/CU (thread-capped) ----
__global__ __launch_bounds__(256) void fused_gather_kernel(
    const int* __restrict__ ccur, const int2* __restrict__ srtA,
    const uint2* __restrict__ fb2,    // feats bf16, 32 uint2/row
    uint2* __restrict__ Abig2)        // 64 uint2/row (sum half, prod half)
{
    __shared__ int2 list[CAP];        // 19 KB
    __shared__ int hist[128], cur[128];

    const int t = threadIdx.x;
    const int b = blockIdx.x;
    const int base = b * CAP;
    const int cnt = ccur[b] - base;

    if (t < 128) hist[t] = 0;
    __syncthreads();

    // phase 1: histogram of dst-low (native int LDS atomics)
    for (int i = t; i < cnt; i += 256)
        atomicAdd(&hist[(unsigned)srtA[base + i].x >> 24], 1);
    __syncthreads();

    // phase 2: exclusive scan of hist[128] by wave 0 -> cur
    if (t < 64) {
        int carry = 0;
#pragma unroll
        for (int c = 0; c < 2; c++) {
            int i = c * 64 + t;
            int x = hist[i], v = x;
#pragma unroll
            for (int d = 1; d < 64; d <<= 1) {
                int y = __shfl_up(v, d);
                if (t >= d) v += y;
            }
            cur[i] = v - x + carry;
            carry += __shfl(v, 63);
        }
    }
    __syncthreads();

    // phase 3: scatter into LDS list at atomic positions (L2-hot re-read)
    for (int i = t; i < cnt; i += 256) {
        int2 e = srtA[base + i];
        int d = (unsigned)e.x >> 24;
        int pos = atomicAdd(&cur[d], 1);
        list[pos] = make_int2(e.x & 0x00FFFFFF, e.y);
    }
    __syncthreads();
    // after scatter: cur[n] == end(n), beg(n) == cur[n] - hist[n]

    // phase 4: 4 waves, each owns 32 nodes, 2 in flight (32 lanes each)
    const int w = t >> 6;
    const int lane = t & 63;
    const int hh = lane >> 5;         // which of the 2 concurrent nodes
    const int l = lane & 31;          // lane within node

    for (int np = 0; np < 32; np += 2) {
        const int nl = w * 32 + np + hh;
        const int end = cur[nl];
        int i = end - hist[nl];

        float a0 = 0.f, a1 = 0.f, a2 = 0.f, a3 = 0.f;
        for (; i + 3 < end; i += 4) {
            int2 e0 = list[i], e1 = list[i + 1], e2 = list[i + 2], e3 = list[i + 3];
            uint2 p0 = fb2[(size_t)e0.x * 32 + l];
            uint2 p1 = fb2[(size_t)e1.x * 32 + l];
            uint2 p2 = fb2[(size_t)e2.x * 32 + l];
            uint2 p3 = fb2[(size_t)e3.x * 32 + l];
            float v0 = __int_as_float(e0.y), v1 = __int_as_float(e1.y);
            float v2 = __int_as_float(e2.y), v3 = __int_as_float(e3.y);
            a0 += v0 * __uint_as_float(p0.x << 16) + v1 * __uint_as_float(p1.x << 16)
                + v2 * __uint_as_float(p2.x << 16) + v3 * __uint_as_float(p3.x << 16);
            a1 += v0 * __uint_as_float(p0.x & 0xffff0000u) + v1 * __uint_as_float(p1.x & 0xffff0000u)
                + v2 * __uint_as_float(p2.x & 0xffff0000u) + v3 * __uint_as_float(p3.x & 0xffff0000u);
            a2 += v0 * __uint_as_float(p0.y << 16) + v1 * __uint_as_float(p1.y << 16)
                + v2 * __uint_as_float(p2.y << 16) + v3 * __uint_as_float(p3.y << 16);
            a3 += v0 * __uint_as_float(p0.y & 0xffff0000u) + v1 * __uint_as_float(p1.y & 0xffff0000u)
                + v2 * __uint_as_float(p2.y & 0xffff0000u) + v3 * __uint_as_float(p3.y & 0xffff0000u);
        }
        for (; i < end; i++) {
            int2 e0 = list[i];
            uint2 p0 = fb2[(size_t)e0.x * 32 + l];
            float v0 = __int_as_float(e0.y);
            a0 += v0 * __uint_as_float(p0.x << 16);
            a1 += v0 * __uint_as_float(p0.x & 0xffff0000u);
            a2 += v0 * __uint_as_float(p0.y << 16);
            a3 += v0 * __uint_as_float(p0.y & 0xffff0000u);
        }

        const int gn = b * 128 + nl;
        if (gn < N_NODES) {
            uint2 pf = fb2[(size_t)gn * 32 + l];
            float f0 = __uint_as_float(pf.x << 16);
            float f1 = __uint_as_float(pf.x & 0xffff0000u);
            float f2v = __uint_as_float(pf.y << 16);
            float f3 = __uint_as_float(pf.y & 0xffff0000u);

            uint2 S, P;
            S.x = pack_bf16(a0 + f0, a1 + f1);  S.y = pack_bf16(a2 + f2v, a3 + f3);
            P.x = pack_bf16(a0 * f0, a1 * f1);  P.y = pack_bf16(a2 * f2v, a3 * f3);
            Abig2[(size_t)gn * 64 + l]      = S;
            Abig2[(size_t)gn * 64 + 32 + l] = P;
        }
    }
}

// ---- GEMM: out = Abig[M x 256] @ Wb[128 x 256]^T + b1 + b2 (no LDS, no barrier)
__global__ __launch_bounds__(256) void gemm_kernel(
    const unsigned short* __restrict__ Abig, const unsigned short* __restrict__ Wb,
    const float* __restrict__ b1, const float* __restrict__ b2,
    float* __restrict__ out)
{
    const int t = threadIdx.x;
    const int w = t >> 6, lane = t & 63;
    const int col = lane & 15;
    const int quad = lane >> 4;
    const int ko = quad * 8;
    const int m0 = blockIdx.x * 64 + w * 16;

    float4v acc[8];
#pragma unroll
    for (int j = 0; j < 8; j++) acc[j] = (float4v)(0.f);

    const unsigned short* arow = Abig + (size_t)(m0 + col) * 256 + ko;
#pragma unroll
    for (int k0 = 0; k0 < 8; k0++) {
        short8 a = *(const short8*)(arow + k0 * 32);
#pragma unroll
        for (int j = 0; j < 8; j++) {
            short8 b = *(const short8*)&Wb[(size_t)(j * 16 + col) * 256 + k0 * 32 + ko];
            acc[j] = __builtin_amdgcn_mfma_f32_16x16x32_bf16(a, b, acc[j], 0, 0, 0);
        }
    }

#pragma unroll
    for (int j = 0; j < 8; j++) {
        int n0 = j * 16 + col;
        float bb = b1[n0] + b2[n0];
#pragma unroll
        for (int r = 0; r < 4; r++) {
            int m = m0 + quad * 4 + r;
            if (m < N_NODES)
                __builtin_nontemporal_store(acc[j][r] + bb, &out[(size_t)m * F + n0]);
        }
    }
}

extern "C" void kernel_launch(void* const* d_in, const int* in_sizes, int n_in,
                              void* d_out, int out_size, void* d_ws, size_t ws_size,
                              hipStream_t stream) {
    const int*   edge_src  = (const int*)d_in[0];
    const int*   edge_dst  = (const int*)d_in[1];
    const float* edge_vals = (const float*)d_in[2];
    const float* feats     = (const float*)d_in[3];
    const float* W1        = (const float*)d_in[4];
    const float* b1        = (const float*)d_in[5];
    const float* W2        = (const float*)d_in[6];
    const float* b2        = (const float*)d_in[7];
    float* out = (float*)d_out;

    // Workspace layout (bytes):
    char* ws = (char*)d_ws;
    unsigned*       featsb = (unsigned*)      (ws);             // 25,600,000
    int2*           srtA   = (int2*)          (ws + 25600000);  // 15,214,592 (782*2432*8)
    int*            ccur   = (int*)           (ws + 40814592);  //      4,096 (3128 used)
    unsigned*       Wbu    = (unsigned*)      (ws + 40818688);  //     65,536
    unsigned short* Abig   = (unsigned short*)(ws + 40884224);  // 51,216,384 (M_PAD*256*2)
                                                                // end ~92.1 MB

    prep_kernel<<<FB_BLOCKS + W_BLOCKS + CC_BLOCKS, 256, 0, stream>>>(
        (const float4*)feats, (uint4*)featsb, W1, W2, Wbu, ccur);

    passA_kernel<<<MS_BLOCKS, 256, 0, stream>>>(
        edge_src, edge_dst, edge_vals, ccur, srtA);

    fused_gather_kernel<<<NCB, 256, 0, stream>>>(
        ccur, srtA, (const uint2*)featsb, (uint2*)Abig);

    gemm_kernel<<<M_PAD / 64, 256, 0, stream>>>(
        Abig, (const unsigned short*)Wbu, b1, b2, out);
}

// Round 10
// 274.424 us; speedup vs baseline: 1.0479x; 1.0479x over previous
//
#include <hip/hip_runtime.h>

#define N_NODES 100000
#define N_EDGES 1600000
#define F 128
#define M_PAD 100032       // N_NODES rounded up to 64
#define NCB 782            // buckets = ceil(N_NODES/128)
#define CAP 2432           // padded bucket capacity (mean 2048, sigma 45, +8.5 sigma)
#define EPB 4096           // edges per multisplit block (R7-proven best)
#define MS_BLOCKS 391      // ceil(N_EDGES/EPB)
#define FCHUNK 4093        // feats uint4 per passA block: ceil(1,600,000/391)
#define LCAP 1536          // fused half-bucket list capacity (mean 1024, sigma 32, +16 sigma)

typedef __attribute__((ext_vector_type(8))) short short8;
typedef __attribute__((ext_vector_type(4))) float float4v;

__device__ __forceinline__ unsigned pack_bf16(float x, float y) {
    unsigned ux = __float_as_uint(x), uy = __float_as_uint(y);
    ux = (ux + 0x7fffu + ((ux >> 16) & 1u)) >> 16;       // RNE
    uy = (uy + 0x7fffu + ((uy >> 16) & 1u)) >> 16;
    return ux | (uy << 16);
}

// ---- Pass A: multisplit into 128-node buckets; dst-low(7b) in bits 24..31.
//      ccur holds COUNTS (memset 0); dest base = b*CAP.
//      feats/W bf16 conversion folded into the scan window (waves 1-3 idle there).
//      LDS 47.2 KB -> 3 blocks/CU ----
__global__ __launch_bounds__(256) void passA_kernel(
    const int* __restrict__ esrc, const int* __restrict__ edst,
    const float* __restrict__ evals, int* __restrict__ ccur,
    int2* __restrict__ srtA,
    const float4* __restrict__ feats4, uint4* __restrict__ featsb4,
    const float* __restrict__ W1, const float* __restrict__ W2,
    unsigned* __restrict__ Wbu)
{
    __shared__ int2 sv[EPB];              // 32 KB
    __shared__ unsigned short bkt[EPB];   //  8 KB
    __shared__ int h[NCB], lo[NCB];       //  6.3 KB  (total 47.2 KB)

    const int t = threadIdx.x;
    const int blk = blockIdx.x;
    const int base = blk * EPB;
    const int cnt = min(EPB, N_EDGES - base);

    for (int i = t; i < NCB; i += 256) h[i] = 0;
    __syncthreads();

    int rsrc[16], rdst[16], rrank[16];
    float rval[16];
#pragma unroll
    for (int i = 0; i < 16; i++) {
        int e = base + i * 256 + t;
        if (e < N_EDGES) {
            rsrc[i] = esrc[e];
            rdst[i] = edst[e];
            rval[i] = evals[e];
            rrank[i] = atomicAdd(&h[rdst[i] >> 7], 1);
        } else rdst[i] = -1;
    }
    __syncthreads();

    if (t < 64) {   // wave 0: exclusive scan of h over 782 buckets
        int carry = 0;
        for (int b0 = 0; b0 < NCB; b0 += 64) {
            int i = b0 + t;
            int x = (i < NCB) ? h[i] : 0;
            int v = x;
#pragma unroll
            for (int d = 1; d < 64; d <<= 1) {
                int y = __shfl_up(v, d);
                if (t >= d) v += y;
            }
            if (i < NCB) lo[i] = v - x + carry;
            carry += __shfl(v, 63);
        }
    } else {        // waves 1-3: stream feats (+W) bf16 conversion in the idle window
        const int tc = t - 64;                        // 0..191
        if (blk < 64) {                               // W: 64 blocks x 256 uints
            for (int i = tc; i < 256; i += 192) {
                int gi = blk * 256 + i;               // < 16384
                int j = gi >> 7, c = gi & 127;
                const float* s = (c < 64) ? &W1[j * 128 + 2 * c]
                                          : &W2[j * 128 + 2 * (c - 64)];
                Wbu[gi] = pack_bf16(s[0], s[1]);
            }
        }
        const int f0 = blk * FCHUNK;
        const int fend = min(f0 + FCHUNK, 1600000);
        for (int i = f0 + tc; i < fend; i += 192) {
            float4 v0 = feats4[2 * i], v1 = feats4[2 * i + 1];
            featsb4[i] = make_uint4(pack_bf16(v0.x, v0.y), pack_bf16(v0.z, v0.w),
                                    pack_bf16(v1.x, v1.y), pack_bf16(v1.z, v1.w));
        }
    }
    __syncthreads();

#pragma unroll
    for (int i = 0; i < 16; i++) {
        if (rdst[i] >= 0) {
            int b = rdst[i] >> 7;
            int s = lo[b] + rrank[i];
            sv[s]  = make_int2(rsrc[i] | ((rdst[i] & 127) << 24),
                               __float_as_int(rval[i]));
            bkt[s] = (unsigned short)b;
        }
    }
    __syncthreads();     // protect lo[] reads above before overwriting below

    // reserve global space; fold dest-base into lo: lo[b] := gdest - local_lo
    for (int b = t; b < NCB; b += 256) {
        int c = h[b];
        if (c) {
            int g = b * CAP + atomicAdd(&ccur[b], c);
            lo[b] = g - lo[b];
        }
    }
    __syncthreads();

    for (int s = t; s < cnt; s += 256)
        srtA[lo[bkt[s]] + s] = sv[s];
}

// ---- fused sort+gather, 2 blocks per bucket (64-node halves):
//      filter bucket slice by half -> LDS fine sort (int atomics) ->
//      register-accum gather -> bf16 Abig.  LDS 12.8 KB -> grid 1564, ~52% occ ----
__global__ __launch_bounds__(256) void fused_gather_kernel(
    const int* __restrict__ ccur, const int2* __restrict__ srtA,
    const uint2* __restrict__ fb2,    // feats bf16, 32 uint2/row
    uint2* __restrict__ Abig2)        // 64 uint2/row (sum half, prod half)
{
    __shared__ int hist[64], cur[64];
    __shared__ int2 list[LCAP];       // 12 KB

    const int t = threadIdx.x;
    const int bb = blockIdx.x;
    const int b = bb >> 1;            // bucket
    const int hf = bb & 1;            // which 64-node half
    const int base = b * CAP;
    const int cnt = ccur[b];          // count (dest base was b*CAP)

    if (t < 64) hist[t] = 0;
    __syncthreads();

    // phase 1: histogram of this half's dst-low (native int LDS atomics)
    for (int i = t; i < cnt; i += 256) {
        int d = (unsigned)srtA[base + i].x >> 24;
        if ((d >> 6) == hf) atomicAdd(&hist[d & 63], 1);
    }
    __syncthreads();

    // phase 2: exclusive scan of hist[64] by wave 0 -> cur
    if (t < 64) {
        int x = hist[t], v = x;
#pragma unroll
        for (int d = 1; d < 64; d <<= 1) {
            int y = __shfl_up(v, d);
            if (t >= d) v += y;
        }
        cur[t] = v - x;
    }
    __syncthreads();

    // phase 3: scatter this half's edges into LDS list (L2-hot re-read)
    for (int i = t; i < cnt; i += 256) {
        int2 e = srtA[base + i];
        int d = (unsigned)e.x >> 24;
        if ((d >> 6) == hf) {
            int pos = atomicAdd(&cur[d & 63], 1);
            list[pos] = make_int2(e.x & 0x00FFFFFF, e.y);
        }
    }
    __syncthreads();
    // after scatter: cur[n] == end(n), beg(n) == cur[n] - hist[n]

    // phase 4: 4 waves, each owns 16 nodes, 2 in flight (32 lanes each)
    const int w = t >> 6;
    const int lane = t & 63;
    const int hh = lane >> 5;         // which of the 2 concurrent nodes
    const int l = lane & 31;          // lane within node

#pragma unroll
    for (int np = 0; np < 16; np += 2) {
        const int nl = w * 16 + np + hh;
        const int end = cur[nl];
        int i = end - hist[nl];

        float a0 = 0.f, a1 = 0.f, a2 = 0.f, a3 = 0.f;
        for (; i + 3 < end; i += 4) {
            int2 e0 = list[i], e1 = list[i + 1], e2 = list[i + 2], e3 = list[i + 3];
            uint2 p0 = fb2[(size_t)e0.x * 32 + l];
            uint2 p1 = fb2[(size_t)e1.x * 32 + l];
            uint2 p2 = fb2[(size_t)e2.x * 32 + l];
            uint2 p3 = fb2[(size_t)e3.x * 32 + l];
            float v0 = __int_as_float(e0.y), v1 = __int_as_float(e1.y);
            float v2 = __int_as_float(e2.y), v3 = __int_as_float(e3.y);
            a0 += v0 * __uint_as_float(p0.x << 16) + v1 * __uint_as_float(p1.x << 16)
                + v2 * __uint_as_float(p2.x << 16) + v3 * __uint_as_float(p3.x << 16);
            a1 += v0 * __uint_as_float(p0.x & 0xffff0000u) + v1 * __uint_as_float(p1.x & 0xffff0000u)
                + v2 * __uint_as_float(p2.x & 0xffff0000u) + v3 * __uint_as_float(p3.x & 0xffff0000u);
            a2 += v0 * __uint_as_float(p0.y << 16) + v1 * __uint_as_float(p1.y << 16)
                + v2 * __uint_as_float(p2.y << 16) + v3 * __uint_as_float(p3.y << 16);
            a3 += v0 * __uint_as_float(p0.y & 0xffff0000u) + v1 * __uint_as_float(p1.y & 0xffff0000u)
                + v2 * __uint_as_float(p2.y & 0xffff0000u) + v3 * __uint_as_float(p3.y & 0xffff0000u);
        }
        for (; i < end; i++) {
            int2 e0 = list[i];
            uint2 p0 = fb2[(size_t)e0.x * 32 + l];
            float v0 = __int_as_float(e0.y);
            a0 += v0 * __uint_as_float(p0.x << 16);
            a1 += v0 * __uint_as_float(p0.x & 0xffff0000u);
            a2 += v0 * __uint_as_float(p0.y << 16);
            a3 += v0 * __uint_as_float(p0.y & 0xffff0000u);
        }

        const int gn = b * 128 + hf * 64 + nl;
        if (gn < N_NODES) {
            uint2 pf = fb2[(size_t)gn * 32 + l];
            float f0 = __uint_as_float(pf.x << 16);
            float f1 = __uint_as_float(pf.x & 0xffff0000u);
            float f2v = __uint_as_float(pf.y << 16);
            float f3 = __uint_as_float(pf.y & 0xffff0000u);

            uint2 S, P;
            S.x = pack_bf16(a0 + f0, a1 + f1);  S.y = pack_bf16(a2 + f2v, a3 + f3);
            P.x = pack_bf16(a0 * f0, a1 * f1);  P.y = pack_bf16(a2 * f2v, a3 * f3);
            Abig2[(size_t)gn * 64 + l]      = S;
            Abig2[(size_t)gn * 64 + 32 + l] = P;
        }
    }
}

// ---- GEMM: out = Abig[M x 256] @ Wb[128 x 256]^T + b1 + b2 (no LDS, no barrier)
__global__ __launch_bounds__(256) void gemm_kernel(
    const unsigned short* __restrict__ Abig, const unsigned short* __restrict__ Wb,
    const float* __restrict__ b1, const float* __restrict__ b2,
    float* __restrict__ out)
{
    const int t = threadIdx.x;
    const int w = t >> 6, lane = t & 63;
    const int col = lane & 15;
    const int quad = lane >> 4;
    const int ko = quad * 8;
    const int m0 = blockIdx.x * 64 + w * 16;

    float4v acc[8];
#pragma unroll
    for (int j = 0; j < 8; j++) acc[j] = (float4v)(0.f);

    const unsigned short* arow = Abig + (size_t)(m0 + col) * 256 + ko;
#pragma unroll
    for (int k0 = 0; k0 < 8; k0++) {
        short8 a = *(const short8*)(arow + k0 * 32);
#pragma unroll
        for (int j = 0; j < 8; j++) {
            short8 b = *(const short8*)&Wb[(size_t)(j * 16 + col) * 256 + k0 * 32 + ko];
            acc[j] = __builtin_amdgcn_mfma_f32_16x16x32_bf16(a, b, acc[j], 0, 0, 0);
        }
    }

#pragma unroll
    for (int j = 0; j < 8; j++) {
        int n0 = j * 16 + col;
        float bb = b1[n0] + b2[n0];
#pragma unroll
        for (int r = 0; r < 4; r++) {
            int m = m0 + quad * 4 + r;
            if (m < N_NODES)
                __builtin_nontemporal_store(acc[j][r] + bb, &out[(size_t)m * F + n0]);
        }
    }
}

extern "C" void kernel_launch(void* const* d_in, const int* in_sizes, int n_in,
                              void* d_out, int out_size, void* d_ws, size_t ws_size,
                              hipStream_t stream) {
    const int*   edge_src  = (const int*)d_in[0];
    const int*   edge_dst  = (const int*)d_in[1];
    const float* edge_vals = (const float*)d_in[2];
    const float* feats     = (const float*)d_in[3];
    const float* W1        = (const float*)d_in[4];
    const float* b1        = (const float*)d_in[5];
    const float* W2        = (const float*)d_in[6];
    const float* b2        = (const float*)d_in[7];
    float* out = (float*)d_out;

    // Workspace layout (bytes):
    char* ws = (char*)d_ws;
    unsigned*       featsb = (unsigned*)      (ws);             // 25,600,000
    int2*           srtA   = (int2*)          (ws + 25600000);  // 15,214,592 (782*2432*8)
    int*            ccur   = (int*)           (ws + 40814592);  //      4,096 (3128 used)
    unsigned*       Wbu    = (unsigned*)      (ws + 40818688);  //     65,536
    unsigned short* Abig   = (unsigned short*)(ws + 40884224);  // 51,216,384 (M_PAD*256*2)
                                                                // end ~92.1 MB

    hipMemsetAsync(ccur, 0, NCB * sizeof(int), stream);

    passA_kernel<<<MS_BLOCKS, 256, 0, stream>>>(
        edge_src, edge_dst, edge_vals, ccur, srtA,
        (const float4*)feats, (uint4*)featsb, W1, W2, Wbu);

    fused_gather_kernel<<<2 * NCB, 256, 0, stream>>>(
        ccur, srtA, (const uint2*)featsb, (uint2*)Abig);

    gemm_kernel<<<M_PAD / 64, 256, 0, stream>>>(
        Abig, (const unsigned short*)Wbu, b1, b2, out);
}